// Round 1
// baseline (1050.505 us; speedup 1.0000x reference)
//
#include <hip/hip_runtime.h>
#include <math.h>

#define T_TOK 25600   // B*L = 128*200
#define HDIM  128
#define SEQL  200

__device__ __forceinline__ float wave_sum64(float v) {
#pragma unroll
  for (int off = 32; off > 0; off >>= 1) v += __shfl_xor(v, off, 64);
  return v;
}

// ---------------- item gather + pos + LayerNorm(eps=1e-12) ----------------
__global__ __launch_bounds__(256) void seq_ln_kernel(
    const int* __restrict__ ids, const float* __restrict__ item,
    const float* __restrict__ pos, const float* __restrict__ lw,
    const float* __restrict__ lb, float* __restrict__ seq) {
  const int lane = threadIdx.x & 63;
  const int tok  = blockIdx.x * 4 + (threadIdx.x >> 6);
  const int id   = ids[tok];
  const int pl   = tok % SEQL;
  float x0 = item[(size_t)id * HDIM + lane]      + pos[pl * HDIM + lane];
  float x1 = item[(size_t)id * HDIM + 64 + lane] + pos[pl * HDIM + 64 + lane];
  float mean = wave_sum64(x0 + x1) * (1.0f / HDIM);
  float d0 = x0 - mean, d1 = x1 - mean;
  float var = wave_sum64(d0 * d0 + d1 * d1) * (1.0f / HDIM);
  float inv = rsqrtf(var + 1e-12f);
  seq[(size_t)tok * HDIM + lane]      = d0 * inv * lw[lane] + lb[lane];
  seq[(size_t)tok * HDIM + 64 + lane] = d1 * inv * lw[64 + lane] + lb[64 + lane];
}

// ---------------- row-wise l2 normalize, in place ----------------
__global__ __launch_bounds__(256) void l2norm_kernel(float* __restrict__ X) {
  const int lane = threadIdx.x & 63;
  const int tok  = blockIdx.x * 4 + (threadIdx.x >> 6);
  float x0 = X[(size_t)tok * HDIM + lane];
  float x1 = X[(size_t)tok * HDIM + 64 + lane];
  float s  = wave_sum64(x0 * x0 + x1 * x1);
  float sc = 1.0f / fmaxf(sqrtf(s), 1e-12f);
  X[(size_t)tok * HDIM + lane]      = x0 * sc;
  X[(size_t)tok * HDIM + 64 + lane] = x1 * sc;
}

// ---------------- generic GEMM  C[T,128] = A(rows)[.,K] @ W[128,K]^T + bias -------
// A rows optionally gathered via idx. BM=64, BN=128, BK=32, 256 threads.
__global__ __launch_bounds__(256) void gemm_bt_kernel(
    const float* __restrict__ A, const int* __restrict__ idx,
    const float* __restrict__ W, const float* __restrict__ bias,
    float* __restrict__ C, int K, int lda) {
  __shared__ float As[64][33];
  __shared__ float Ws[32][128];
  const int t = threadIdx.x;
  const int tile = blockIdx.x;
  const int tm = t >> 4, tn = t & 15;
  const int am = t >> 2, ak = (t & 3) * 8;
  const int wn = t >> 1, wk = (t & 1) * 16;
  const int arow = tile * 64 + am;
  const float* Arow = A + (size_t)(idx ? idx[arow] : arow) * lda;
  const float* Wrow = W + (size_t)wn * K + wk;

  float acc[4][8];
#pragma unroll
  for (int i = 0; i < 4; i++)
#pragma unroll
    for (int j = 0; j < 8; j++) acc[i][j] = 0.0f;

  for (int kb = 0; kb < K; kb += 32) {
    float4 a0 = *(const float4*)(Arow + kb + ak);
    float4 a1 = *(const float4*)(Arow + kb + ak + 4);
    float4 w0 = *(const float4*)(Wrow + kb);
    float4 w1 = *(const float4*)(Wrow + kb + 4);
    float4 w2 = *(const float4*)(Wrow + kb + 8);
    float4 w3 = *(const float4*)(Wrow + kb + 12);
    __syncthreads();
    As[am][ak + 0] = a0.x; As[am][ak + 1] = a0.y; As[am][ak + 2] = a0.z; As[am][ak + 3] = a0.w;
    As[am][ak + 4] = a1.x; As[am][ak + 5] = a1.y; As[am][ak + 6] = a1.z; As[am][ak + 7] = a1.w;
    Ws[wk +  0][wn] = w0.x; Ws[wk +  1][wn] = w0.y; Ws[wk +  2][wn] = w0.z; Ws[wk +  3][wn] = w0.w;
    Ws[wk +  4][wn] = w1.x; Ws[wk +  5][wn] = w1.y; Ws[wk +  6][wn] = w1.z; Ws[wk +  7][wn] = w1.w;
    Ws[wk +  8][wn] = w2.x; Ws[wk +  9][wn] = w2.y; Ws[wk + 10][wn] = w2.z; Ws[wk + 11][wn] = w2.w;
    Ws[wk + 12][wn] = w3.x; Ws[wk + 13][wn] = w3.y; Ws[wk + 14][wn] = w3.z; Ws[wk + 15][wn] = w3.w;
    __syncthreads();
#pragma unroll
    for (int kk = 0; kk < 32; kk++) {
      float av[4];
#pragma unroll
      for (int i = 0; i < 4; i++) av[i] = As[tm * 4 + i][kk];
      float4 wv0 = *(const float4*)&Ws[kk][tn * 8];
      float4 wv1 = *(const float4*)&Ws[kk][tn * 8 + 4];
      float wv[8] = {wv0.x, wv0.y, wv0.z, wv0.w, wv1.x, wv1.y, wv1.z, wv1.w};
#pragma unroll
      for (int i = 0; i < 4; i++)
#pragma unroll
        for (int j = 0; j < 8; j++) acc[i][j] += av[i] * wv[j];
    }
  }
  float bj[8];
#pragma unroll
  for (int j = 0; j < 8; j++) bj[j] = bias[tn * 8 + j];
#pragma unroll
  for (int i = 0; i < 4; i++) {
    const int row = tile * 64 + tm * 4 + i;
    float* Crow = C + (size_t)row * 128 + tn * 8;
    float4 o0 = make_float4(acc[i][0] + bj[0], acc[i][1] + bj[1], acc[i][2] + bj[2], acc[i][3] + bj[3]);
    float4 o1 = make_float4(acc[i][4] + bj[4], acc[i][5] + bj[5], acc[i][6] + bj[6], acc[i][7] + bj[7]);
    *(float4*)Crow = o0;
    *(float4*)(Crow + 4) = o1;
  }
}

// ---------------- z = mu + exp(sg) * noise ----------------
__global__ __launch_bounds__(256) void vae_kernel(
    const float* __restrict__ mu, const float* __restrict__ sg,
    const float* __restrict__ noise, float* __restrict__ z) {
  const size_t i = ((size_t)blockIdx.x * 256 + threadIdx.x) * 4;
  float4 m = *(const float4*)(mu + i);
  float4 s = *(const float4*)(sg + i);
  float4 n = *(const float4*)(noise + i);
  float4 o;
  o.x = m.x + expf(s.x) * n.x;
  o.y = m.y + expf(s.y) * n.y;
  o.z = m.z + expf(s.z) * n.z;
  o.w = m.w + expf(s.w) * n.w;
  *(float4*)(z + i) = o;
}

// ---------------- softmax gate -> top2 -> renormalize ----------------
__global__ __launch_bounds__(256) void gate_kernel(
    const float* __restrict__ Z, const float* __restrict__ GW,
    const float* __restrict__ GB, float* __restrict__ G) {
  const int lane = threadIdx.x & 63;
  const int tok  = blockIdx.x * 4 + (threadIdx.x >> 6);
  float z0 = Z[(size_t)tok * HDIM + lane];
  float z1 = Z[(size_t)tok * HDIM + 64 + lane];
  float p[8];
#pragma unroll
  for (int e = 0; e < 8; e++)
    p[e] = z0 * GW[e * HDIM + lane] + z1 * GW[e * HDIM + 64 + lane];
#pragma unroll
  for (int off = 32; off > 0; off >>= 1)
#pragma unroll
    for (int e = 0; e < 8; e++) p[e] += __shfl_xor(p[e], off, 64);
  if (lane == 0) {
    float lg[8];
    float m = -1e30f;
#pragma unroll
    for (int e = 0; e < 8; e++) { lg[e] = p[e] + GB[e]; m = fmaxf(m, lg[e]); }
    float ex[8], s = 0.0f;
#pragma unroll
    for (int e = 0; e < 8; e++) { ex[e] = expf(lg[e] - m); s += ex[e]; }
    int i1 = 0;
#pragma unroll
    for (int e = 1; e < 8; e++) if (ex[e] > ex[i1]) i1 = e;
    int i2 = (i1 == 0) ? 1 : 0;
#pragma unroll
    for (int e = 0; e < 8; e++) if (e != i1 && ex[e] > ex[i2]) i2 = e;
    float w1 = ex[i1] / s, w2 = ex[i2] / s;
    float d = w1 + w2 + 1e-8f;
    float out[8] = {0, 0, 0, 0, 0, 0, 0, 0};
    out[i1] = w1 / d; out[i2] = w2 / d;
#pragma unroll
    for (int e = 0; e < 8; e++) G[(size_t)tok * 8 + e] = out[e];
  }
}

// ---------------- dense 8-expert weighted GEMM  ----------------
// out[t, col_off:col_off+128] = sum_e G[t,e] * (Z[t,:] @ We^T + be)
__global__ __launch_bounds__(256) void expert_kernel(
    const float* __restrict__ Z, const float* __restrict__ Wexp,
    const float* __restrict__ Bexp, const float* __restrict__ G,
    float* __restrict__ C, int col_off) {
  __shared__ float As[64][129];   // full K=128 A tile, staged once
  __shared__ float Ws[32][128];
  const int t = threadIdx.x;
  const int tile = blockIdx.x;
  const int tm = t >> 4, tn = t & 15;
  const int am = t >> 2, ak0 = (t & 3) * 32;
  const int wn = t >> 1, wk = (t & 1) * 16;

  const float* Zrow = Z + (size_t)(tile * 64 + am) * 128;
#pragma unroll
  for (int q = 0; q < 32; q += 4) {
    float4 v = *(const float4*)(Zrow + ak0 + q);
    As[am][ak0 + q + 0] = v.x; As[am][ak0 + q + 1] = v.y;
    As[am][ak0 + q + 2] = v.z; As[am][ak0 + q + 3] = v.w;
  }

  float acc[4][8];
#pragma unroll
  for (int i = 0; i < 4; i++)
#pragma unroll
    for (int j = 0; j < 8; j++) acc[i][j] = 0.0f;

  for (int e = 0; e < 8; e++) {
    float tmp[4][8];
#pragma unroll
    for (int i = 0; i < 4; i++)
#pragma unroll
      for (int j = 0; j < 8; j++) tmp[i][j] = 0.0f;

    for (int kb = 0; kb < 128; kb += 32) {
      const float* Wrow = Wexp + ((size_t)e * 128 + wn) * 128 + kb + wk;
      float4 w0 = *(const float4*)(Wrow);
      float4 w1 = *(const float4*)(Wrow + 4);
      float4 w2 = *(const float4*)(Wrow + 8);
      float4 w3 = *(const float4*)(Wrow + 12);
      __syncthreads();
      Ws[wk +  0][wn] = w0.x; Ws[wk +  1][wn] = w0.y; Ws[wk +  2][wn] = w0.z; Ws[wk +  3][wn] = w0.w;
      Ws[wk +  4][wn] = w1.x; Ws[wk +  5][wn] = w1.y; Ws[wk +  6][wn] = w1.z; Ws[wk +  7][wn] = w1.w;
      Ws[wk +  8][wn] = w2.x; Ws[wk +  9][wn] = w2.y; Ws[wk + 10][wn] = w2.z; Ws[wk + 11][wn] = w2.w;
      Ws[wk + 12][wn] = w3.x; Ws[wk + 13][wn] = w3.y; Ws[wk + 14][wn] = w3.z; Ws[wk + 15][wn] = w3.w;
      __syncthreads();
#pragma unroll
      for (int kk = 0; kk < 32; kk++) {
        float av[4];
#pragma unroll
        for (int i = 0; i < 4; i++) av[i] = As[tm * 4 + i][kb + kk];
        float4 wv0 = *(const float4*)&Ws[kk][tn * 8];
        float4 wv1 = *(const float4*)&Ws[kk][tn * 8 + 4];
        float wv[8] = {wv0.x, wv0.y, wv0.z, wv0.w, wv1.x, wv1.y, wv1.z, wv1.w};
#pragma unroll
        for (int i = 0; i < 4; i++)
#pragma unroll
          for (int j = 0; j < 8; j++) tmp[i][j] += av[i] * wv[j];
      }
    }
    float g[4], be[8];
#pragma unroll
    for (int i = 0; i < 4; i++) g[i] = G[(size_t)(tile * 64 + tm * 4 + i) * 8 + e];
#pragma unroll
    for (int j = 0; j < 8; j++) be[j] = Bexp[e * 128 + tn * 8 + j];
#pragma unroll
    for (int i = 0; i < 4; i++)
#pragma unroll
      for (int j = 0; j < 8; j++) acc[i][j] += g[i] * (tmp[i][j] + be[j]);
  }
#pragma unroll
  for (int i = 0; i < 4; i++) {
    const int row = tile * 64 + tm * 4 + i;
    float* Crow = C + (size_t)row * 256 + col_off + tn * 8;
    *(float4*)Crow       = make_float4(acc[i][0], acc[i][1], acc[i][2], acc[i][3]);
    *(float4*)(Crow + 4) = make_float4(acc[i][4], acc[i][5], acc[i][6], acc[i][7]);
  }
}

// ---------------- final: out = seq + relu(LN(y, eps=1e-5)*w+b) ----------------
__global__ __launch_bounds__(256) void fusion_ln_kernel(
    const float* __restrict__ y, const float* __restrict__ seq,
    const float* __restrict__ lw, const float* __restrict__ lb,
    float* __restrict__ out) {
  const int lane = threadIdx.x & 63;
  const int tok  = blockIdx.x * 4 + (threadIdx.x >> 6);
  float x0 = y[(size_t)tok * HDIM + lane];
  float x1 = y[(size_t)tok * HDIM + 64 + lane];
  float mean = wave_sum64(x0 + x1) * (1.0f / HDIM);
  float d0 = x0 - mean, d1 = x1 - mean;
  float var = wave_sum64(d0 * d0 + d1 * d1) * (1.0f / HDIM);
  float inv = rsqrtf(var + 1e-5f);
  float h0 = fmaxf(d0 * inv * lw[lane] + lb[lane], 0.0f);
  float h1 = fmaxf(d1 * inv * lw[64 + lane] + lb[64 + lane], 0.0f);
  out[(size_t)tok * HDIM + lane]      = seq[(size_t)tok * HDIM + lane] + h0;
  out[(size_t)tok * HDIM + 64 + lane] = seq[(size_t)tok * HDIM + 64 + lane] + h1;
}

extern "C" void kernel_launch(void* const* d_in, const int* in_sizes, int n_in,
                              void* d_out, int out_size, void* d_ws, size_t ws_size,
                              hipStream_t stream) {
  const int*   ids     = (const int*)d_in[0];
  const float* t_noise = (const float*)d_in[1];
  const float* i_noise = (const float*)d_in[2];
  const float* item    = (const float*)d_in[3];
  const float* pos     = (const float*)d_in[4];
  const float* text    = (const float*)d_in[5];
  const float* img     = (const float*)d_in[6];
  const float* fct_w   = (const float*)d_in[7];
  const float* fct_b   = (const float*)d_in[8];
  const float* fci_w   = (const float*)d_in[9];
  const float* fci_b   = (const float*)d_in[10];
  const float* ln_w    = (const float*)d_in[11];
  const float* ln_b    = (const float*)d_in[12];
  const float* mu_t_w  = (const float*)d_in[13];
  const float* mu_t_b  = (const float*)d_in[14];
  const float* sg_t_w  = (const float*)d_in[15];
  const float* sg_t_b  = (const float*)d_in[16];
  const float* mu_i_w  = (const float*)d_in[17];
  const float* mu_i_b  = (const float*)d_in[18];
  const float* sg_i_w  = (const float*)d_in[19];
  const float* sg_i_b  = (const float*)d_in[20];
  const float* gate_w  = (const float*)d_in[21];
  const float* gate_b  = (const float*)d_in[22];
  const float* texp_w  = (const float*)d_in[23];
  const float* texp_b  = (const float*)d_in[24];
  const float* iexp_w  = (const float*)d_in[25];
  const float* iexp_b  = (const float*)d_in[26];
  const float* fus_w   = (const float*)d_in[27];
  const float* fus_b   = (const float*)d_in[28];
  const float* fus_lw  = (const float*)d_in[29];
  const float* fus_lb  = (const float*)d_in[30];
  float* out = (float*)d_out;

  float* ws = (float*)d_ws;
  const size_t TH = (size_t)T_TOK * HDIM;
  float* seq = ws;               // TH
  float* emb = ws + TH;          // TH   (text_emb, then img_emb)
  float* mu  = ws + 2 * TH;      // TH   (mu buf, later fusion y)
  float* sg  = ws + 3 * TH;      // TH   (sg buf, later gates)
  float* tz  = ws + 4 * TH;      // TH
  float* iz  = ws + 5 * TH;      // TH
  float* cat = ws + 6 * TH;      // 2*TH
  float* y   = mu;               // reuse (mu free after both VAEs)
  float* gt  = sg;               // reuse (sg free after both VAEs)
  float* gi  = sg + (size_t)T_TOK * 8;

  const int tokW  = T_TOK / 4;   // wave-per-token kernels: 6400 blocks
  const int tiles = T_TOK / 64;  // GEMM tiles: 400 blocks
  const int vaeB  = (int)(TH / 1024);  // 3200 blocks

  // 1. seq embedding + LN
  seq_ln_kernel<<<tokW, 256, 0, stream>>>(ids, item, pos, ln_w, ln_b, seq);
  // 2-6. text modality
  gemm_bt_kernel<<<tiles, 256, 0, stream>>>(text, ids, fct_w, fct_b, emb, 768, 768);
  l2norm_kernel<<<tokW, 256, 0, stream>>>(emb);
  gemm_bt_kernel<<<tiles, 256, 0, stream>>>(emb, nullptr, mu_t_w, mu_t_b, mu, 128, 128);
  gemm_bt_kernel<<<tiles, 256, 0, stream>>>(emb, nullptr, sg_t_w, sg_t_b, sg, 128, 128);
  vae_kernel<<<vaeB, 256, 0, stream>>>(mu, sg, t_noise, tz);
  // 7-11. image modality
  gemm_bt_kernel<<<tiles, 256, 0, stream>>>(img, ids, fci_w, fci_b, emb, 512, 512);
  l2norm_kernel<<<tokW, 256, 0, stream>>>(emb);
  gemm_bt_kernel<<<tiles, 256, 0, stream>>>(emb, nullptr, mu_i_w, mu_i_b, mu, 128, 128);
  gemm_bt_kernel<<<tiles, 256, 0, stream>>>(emb, nullptr, sg_i_w, sg_i_b, sg, 128, 128);
  vae_kernel<<<vaeB, 256, 0, stream>>>(mu, sg, i_noise, iz);
  // 12-13. gates (sg buffer now free -> holds gates)
  gate_kernel<<<tokW, 256, 0, stream>>>(tz, gate_w, gate_b, gt);
  gate_kernel<<<tokW, 256, 0, stream>>>(iz, gate_w, gate_b, gi);
  // 14-15. experts -> cat [T, 256]
  expert_kernel<<<tiles, 256, 0, stream>>>(tz, texp_w, texp_b, gt, cat, 0);
  expert_kernel<<<tiles, 256, 0, stream>>>(iz, iexp_w, iexp_b, gi, cat, 128);
  // 16. fusion GEMM (y reuses mu buffer)
  gemm_bt_kernel<<<tiles, 256, 0, stream>>>(cat, nullptr, fus_w, fus_b, y, 256, 256);
  // 17. final LN + relu + residual
  fusion_ln_kernel<<<tokW, 256, 0, stream>>>(y, seq, fus_lw, fus_lb, out);
}